// Round 9
// baseline (687.042 us; speedup 1.0000x reference)
//
#include <hip/hip_runtime.h>
#include <hip/hip_bf16.h>
#include <stdint.h>

typedef __hip_bfloat16 bf16;
typedef __bf16 bf16x8 __attribute__((ext_vector_type(8)));
typedef float f32x4 __attribute__((ext_vector_type(4)));

#define DM   1024
#define LSEQ 2048
#define NH   16
#define DH   64
#define BB   2
#define HID  4096
#define MROWS (BB*LSEQ)   // 4096
#define QLD  (3*DM)       // qkv buffer row stride

__device__ __forceinline__ void load_lds16(const void* g, void* l) {
    __builtin_amdgcn_global_load_lds(
        (const __attribute__((address_space(1))) unsigned int*)g,
        (__attribute__((address_space(3))) unsigned int*)l, 16, 0, 0);
}

// ------------- weight transposes (fp32 [R,C] -> bf16 [C,R]) + rmsnorm(x) ----
// w1 uses interleaved dest rows: feature f -> row 2f (x_proj), 2f+1 (gate).
// Tail blocks (bid>=16384) do rmsnorm_cast of x -> xn (independent work).
__global__ __launch_bounds__(256)
void transpose_all(const float* __restrict__ wqkv, const float* __restrict__ wo,
                   const float* __restrict__ w1, const float* __restrict__ w2,
                   bf16* __restrict__ wqkvT, bf16* __restrict__ woT,
                   bf16* __restrict__ w1T, bf16* __restrict__ w2T,
                   const float* __restrict__ x, const float* __restrict__ scale1,
                   bf16* __restrict__ xn) {
    int bid = blockIdx.x;
    if (bid >= 16384) {   // ---- rmsnorm rows ----
        const int row = bid - 16384, tid = threadIdx.x;
        const float4 v = ((const float4*)(x + (size_t)row * DM))[tid];
        float ss = v.x * v.x + v.y * v.y + v.z * v.z + v.w * v.w;
#pragma unroll
        for (int off = 32; off >= 1; off >>= 1) ss += __shfl_xor(ss, off);
        __shared__ float part[4];
        if ((tid & 63) == 0) part[tid >> 6] = ss;
        __syncthreads();
        const float tot = part[0] + part[1] + part[2] + part[3];
        const float rs = rsqrtf(tot * (1.0f / DM) + 1e-8f);
        const float4 s = ((const float4*)scale1)[tid];
        union { bf16 h[4]; uint2 u; } pk;
        pk.h[0] = __float2bfloat16(v.x * rs * s.x);
        pk.h[1] = __float2bfloat16(v.y * rs * s.y);
        pk.h[2] = __float2bfloat16(v.z * rs * s.z);
        pk.h[3] = __float2bfloat16(v.w * rs * s.w);
        ((uint2*)(xn + (size_t)row * DM))[tid] = pk.u;
        return;
    }
    const float* src; bf16* dst; int R, C, bx, by; bool inter = false;
    if (bid < 3072)       { src = wqkv; dst = wqkvT; R = 1024; C = 3072; bx = bid % 96;  by = bid / 96; }
    else if (bid < 4096)  { bid -= 3072;  src = wo; dst = woT;  R = 1024; C = 1024; bx = bid % 32;  by = bid / 32; }
    else if (bid < 12288) { bid -= 4096;  src = w1; dst = w1T;  R = 1024; C = 8192; bx = bid % 256; by = bid / 256; inter = true; }
    else                  { bid -= 12288; src = w2; dst = w2T;  R = 4096; C = 1024; bx = bid % 32;  by = bid / 32; }
    __shared__ float tile[32][33];
    const int c0 = bx * 32, r0 = by * 32;
    const int tx = threadIdx.x & 31, ty = threadIdx.x >> 5;
#pragma unroll
    for (int i = 0; i < 32; i += 8)
        tile[ty + i][tx] = src[(size_t)(r0 + ty + i) * C + c0 + tx];
    __syncthreads();
#pragma unroll
    for (int i = 0; i < 32; i += 8) {
        const int c = c0 + ty + i;
        const int drow = inter ? ((c < HID) ? 2 * c : 2 * (c - HID) + 1) : c;
        dst[(size_t)drow * R + r0 + tx] = __float2bfloat16(tile[tx][ty + i]);
    }
}

// ------------- V slice of qkv -> vt [BH, DH, L] -----------------------------
__global__ __launch_bounds__(256)
void v_transpose(const bf16* __restrict__ qkv, bf16* __restrict__ vt) {
    const int bh = blockIdx.z, b = bh >> 4, h = bh & 15;
    const int l0 = blockIdx.x * 32, d0 = blockIdx.y * 32;
    __shared__ bf16 tile[32][33];
    const int tx = threadIdx.x & 31, ty = threadIdx.x >> 5;
#pragma unroll
    for (int i = 0; i < 32; i += 8)
        tile[ty + i][tx] = qkv[((size_t)b * LSEQ + l0 + ty + i) * QLD + 2 * DM + h * DH + d0 + tx];
    __syncthreads();
#pragma unroll
    for (int i = 0; i < 32; i += 8)
        vt[((size_t)bh * DH + d0 + ty + i) * LSEQ + l0 + tx] = tile[tx][ty + i];
}

// ------- O-proj reduce: x1 = sum3 partials + b_o + x ; xn2 = rmsnorm(x1)*s2 -
__global__ __launch_bounds__(256)
void oproj_reduce_rmsnorm(const float* __restrict__ part, const float* __restrict__ bias,
                          const float* __restrict__ res, const float* __restrict__ scale,
                          float* __restrict__ x1, bf16* __restrict__ xn2) {
    const int row = blockIdx.x, tid = threadIdx.x;
    const float4 p0 = ((const float4*)(part + (size_t)row * DM))[tid];
    const float4 p1 = ((const float4*)(part + ((size_t)MROWS + row) * DM))[tid];
    const float4 p2 = ((const float4*)(part + ((size_t)2 * MROWS + row) * DM))[tid];
    const float4 bb = ((const float4*)bias)[tid];
    const float4 rr = ((const float4*)(res + (size_t)row * DM))[tid];
    float4 v;
    v.x = p0.x + p1.x + p2.x + bb.x + rr.x;
    v.y = p0.y + p1.y + p2.y + bb.y + rr.y;
    v.z = p0.z + p1.z + p2.z + bb.z + rr.z;
    v.w = p0.w + p1.w + p2.w + bb.w + rr.w;
    ((float4*)(x1 + (size_t)row * DM))[tid] = v;
    float ss = v.x * v.x + v.y * v.y + v.z * v.z + v.w * v.w;
#pragma unroll
    for (int off = 32; off >= 1; off >>= 1) ss += __shfl_xor(ss, off);
    __shared__ float partl[4];
    if ((tid & 63) == 0) partl[tid >> 6] = ss;
    __syncthreads();
    const float tot = partl[0] + partl[1] + partl[2] + partl[3];
    const float rs = rsqrtf(tot * (1.0f / DM) + 1e-8f);
    const float4 s = ((const float4*)scale)[tid];
    union { bf16 h[4]; uint2 u; } pk;
    pk.h[0] = __float2bfloat16(v.x * rs * s.x);
    pk.h[1] = __float2bfloat16(v.y * rs * s.y);
    pk.h[2] = __float2bfloat16(v.z * rs * s.z);
    pk.h[3] = __float2bfloat16(v.w * rs * s.w);
    ((uint2*)(xn2 + (size_t)row * DM))[tid] = pk.u;
}

// ------- FFN2 reduce: out = sum3 partials + b2 + x1 -------------------------
__global__ __launch_bounds__(256)
void ffn2_reduce(const float* __restrict__ part, const float* __restrict__ b2,
                 const float* __restrict__ x1, float* __restrict__ out) {
    const int g = blockIdx.x * 256 + threadIdx.x;   // float4 index over 4096x1024
    const int c4 = g & 255;
    const float4 p0 = ((const float4*)part)[g];
    const float4 p1 = ((const float4*)part)[(size_t)MROWS * 256 + g];
    const float4 p2 = ((const float4*)part)[(size_t)2 * MROWS * 256 + g];
    const float4 bb = ((const float4*)b2)[c4];
    const float4 rr = ((const float4*)x1)[g];
    float4 v;
    v.x = p0.x + p1.x + p2.x + bb.x + rr.x;
    v.y = p0.y + p1.y + p2.y + bb.y + rr.y;
    v.z = p0.z + p1.z + p2.z + bb.z + rr.z;
    v.w = p0.w + p1.w + p2.w + bb.w + rr.w;
    ((float4*)out)[g] = v;
}

// ------------- bf16 GEMM 128x128: C[M,N] = A[M,K] @ Bt[N,K]^T ---------------
// Triple-buffered LDS, one raw s_barrier per K-iter, s_waitcnt vmcnt(4).
// Optional split-K (S>1). XCD panel swizzle for B L2 residency.
template <int KDIM, int NN, int S, typename Epi>
__global__ __launch_bounds__(256, 3)
void gemm_bt(const bf16* __restrict__ A, const bf16* __restrict__ Bt, Epi epi) {
    __shared__ __align__(16) bf16 sA[3][128 * 32];
    __shared__ __align__(16) bf16 sB[3][128 * 32];
    constexpr int NPX = NN / 8;            // n-tiles per XCD panel
    constexpr int MBNB = (MROWS / 128) * NN;
    const int bid = blockIdx.x;
    const int sk = (S > 1) ? bid / MBNB : 0;
    const int ib = (S > 1) ? bid % MBNB : bid;
    const int xcd = ib & 7, loc = ib >> 3;
    const int nb = xcd * NPX + (loc % NPX), mb = loc / NPX;
    const int m0 = mb * 128, n0 = nb * 128;
    const int tid = threadIdx.x;
    const int wave = tid >> 6, lane = tid & 63;
    const int lo = lane & 15, hi = lane >> 4;
    const int wm = wave & 1, wn = wave >> 1;
    const int rowA = lane >> 2, cc = (lane & 3) * 8;
    const int slot0 = wave * 2, slot1 = wave * 2 + 1;

    const bf16* Ag0 = A + (size_t)(m0 + slot0 * 16 + rowA) * KDIM + cc;
    const bf16* Ag1 = A + (size_t)(m0 + slot1 * 16 + rowA) * KDIM + cc;
    const bf16* Bg0 = Bt + (size_t)(n0 + slot0 * 16 + rowA) * KDIM + cc;
    const bf16* Bg1 = Bt + (size_t)(n0 + slot1 * 16 + rowA) * KDIM + cc;

    auto stage = [&](int kt, int buf) {
        const int k0 = kt * 32;
        load_lds16(Ag0 + k0, &sA[buf][slot0 * 512]);
        load_lds16(Ag1 + k0, &sA[buf][slot1 * 512]);
        load_lds16(Bg0 + k0, &sB[buf][slot0 * 512]);
        load_lds16(Bg1 + k0, &sB[buf][slot1 * 512]);
    };

    f32x4 acc[4][4];
#pragma unroll
    for (int i = 0; i < 4; i++)
#pragma unroll
        for (int j = 0; j < 4; j++) acc[i][j] = (f32x4){0.f, 0.f, 0.f, 0.f};

    constexpr int NK = KDIM / 32;
    const int kt0 = (S > 1) ? (sk * NK) / S : 0;
    const int kt1 = (S > 1) ? ((sk + 1) * NK) / S : NK;
    stage(kt0, 0);
    int bc = 0;
    for (int kt = kt0; kt < kt1; ++kt) {
        const int bn = (bc == 2) ? 0 : bc + 1;
        if (kt + 1 < kt1) {
            stage(kt + 1, bn);
            asm volatile("s_waitcnt vmcnt(4)" ::: "memory");  // drain tile kt only
        } else {
            asm volatile("s_waitcnt vmcnt(0)" ::: "memory");
        }
        asm volatile("s_barrier" ::: "memory");               // raw: no vmcnt(0) drain
        const bf16* cA = sA[bc];
        const bf16* cB = sB[bc];
        bf16x8 a[4], b[4];
#pragma unroll
        for (int i = 0; i < 4; i++)
            a[i] = *(const bf16x8*)&cA[(wm * 64 + i * 16 + lo) * 32 + hi * 8];
#pragma unroll
        for (int j = 0; j < 4; j++)
            b[j] = *(const bf16x8*)&cB[(wn * 64 + j * 16 + lo) * 32 + hi * 8];
#pragma unroll
        for (int i = 0; i < 4; i++)
#pragma unroll
            for (int j = 0; j < 4; j++)
                acc[i][j] = __builtin_amdgcn_mfma_f32_16x16x32_bf16(a[i], b[j], acc[i][j], 0, 0, 0);
        bc = bn;
    }
    const int rbase = sk * MROWS + m0;
#pragma unroll
    for (int i = 0; i < 4; i++) {
        const int row = rbase + wm * 64 + i * 16 + hi * 4;
#pragma unroll
        for (int j = 0; j < 4; j++) {
            const int col = n0 + wn * 64 + j * 16 + lo;
#pragma unroll
            for (int r = 0; r < 4; r++) epi(row + r, col, acc[i][j][r]);
        }
    }
}

// ------------- bf16 GEMM 128x256: 4 waves x (64x128 wave tile) --------------
// Halves block-iters and LDS bytes/MAC vs 128x128 (frag 48KB + stage 24KB per
// 1.05M MACs). LDS 72KB -> 2 blocks/CU. Same raw-barrier vmcnt pipeline, 6
// DMAs/wave/iter -> s_waitcnt vmcnt(6). NT256 = #256-wide n-tiles (div by 8).
template <int KDIM, int NT256, typename Epi>
__global__ __launch_bounds__(256, 2)
void gemm_bt256(const bf16* __restrict__ A, const bf16* __restrict__ Bt, Epi epi) {
    __shared__ __align__(16) bf16 sA[3][128 * 32];
    __shared__ __align__(16) bf16 sB[3][256 * 32];
    constexpr int NPX = NT256 / 8;
    const int bid = blockIdx.x;
    const int xcd = bid & 7, loc = bid >> 3;
    const int nb = xcd * NPX + (loc % NPX), mb = loc / NPX;
    const int m0 = mb * 128, n0 = nb * 256;
    const int tid = threadIdx.x;
    const int wave = tid >> 6, lane = tid & 63;
    const int lo = lane & 15, hi = lane >> 4;
    const int wm = wave & 1, wn = wave >> 1;
    const int rowA = lane >> 2, cc = (lane & 3) * 8;
    const int slotA0 = wave * 2, slotA1 = wave * 2 + 1;

    const bf16* Ag0 = A + (size_t)(m0 + slotA0 * 16 + rowA) * KDIM + cc;
    const bf16* Ag1 = A + (size_t)(m0 + slotA1 * 16 + rowA) * KDIM + cc;
    const bf16* Bg[4];
#pragma unroll
    for (int s = 0; s < 4; s++)
        Bg[s] = Bt + (size_t)(n0 + (wave * 4 + s) * 16 + rowA) * KDIM + cc;

    auto stage = [&](int kt, int buf) {
        const int k0 = kt * 32;
        load_lds16(Ag0 + k0, &sA[buf][slotA0 * 512]);
        load_lds16(Ag1 + k0, &sA[buf][slotA1 * 512]);
#pragma unroll
        for (int s = 0; s < 4; s++)
            load_lds16(Bg[s] + k0, &sB[buf][(wave * 4 + s) * 512]);
    };

    f32x4 acc[4][8];
#pragma unroll
    for (int i = 0; i < 4; i++)
#pragma unroll
        for (int j = 0; j < 8; j++) acc[i][j] = (f32x4){0.f, 0.f, 0.f, 0.f};

    constexpr int NK = KDIM / 32;
    stage(0, 0);
    int bc = 0;
    for (int kt = 0; kt < NK; ++kt) {
        const int bn = (bc == 2) ? 0 : bc + 1;
        if (kt + 1 < NK) {
            stage(kt + 1, bn);
            asm volatile("s_waitcnt vmcnt(6)" ::: "memory");  // drain tile kt only
        } else {
            asm volatile("s_waitcnt vmcnt(0)" ::: "memory");
        }
        asm volatile("s_barrier" ::: "memory");
        const bf16* cA = sA[bc];
        const bf16* cB = sB[bc];
        bf16x8 a[4], b[8];
#pragma unroll
        for (int i = 0; i < 4; i++)
            a[i] = *(const bf16x8*)&cA[(wm * 64 + i * 16 + lo) * 32 + hi * 8];
#pragma unroll
        for (int j = 0; j < 8; j++)
            b[j] = *(const bf16x8*)&cB[(wn * 128 + j * 16 + lo) * 32 + hi * 8];
#pragma unroll
        for (int i = 0; i < 4; i++)
#pragma unroll
            for (int j = 0; j < 8; j++)
                acc[i][j] = __builtin_amdgcn_mfma_f32_16x16x32_bf16(a[i], b[j], acc[i][j], 0, 0, 0);
        bc = bn;
    }
#pragma unroll
    for (int i = 0; i < 4; i++) {
        const int row = m0 + wm * 64 + i * 16 + hi * 4;
#pragma unroll
        for (int j = 0; j < 8; j++) {
            const int col = n0 + wn * 128 + j * 16 + lo;
#pragma unroll
            for (int r = 0; r < 4; r++) epi(row + r, col, acc[i][j][r]);
        }
    }
}

// Epilogues
struct EpiBiasBF16 {      // out bf16 = val + bias[col]
    const float* bias; bf16* out; int ldc;
    __device__ void operator()(int row, int col, float val) const {
        out[(size_t)row * ldc + col] = __float2bfloat16(val + bias[col]);
    }
};
struct EpiStoreF32 {      // raw partial store (split-K)
    float* out;
    __device__ void operator()(int row, int col, float val) const {
        out[(size_t)row * DM + col] = val;
    }
};
struct EpiSwiGLU {        // interleaved cols: even=x_proj feature col/2, odd=gate
    const float* b1; bf16* out;
    __device__ void operator()(int row, int col, float val) const {
        const int orig = (col >> 1) + ((col & 1) ? HID : 0);
        const float v = val + b1[orig];
        const float other = __shfl_xor(v, 1);
        const float g = other;
        const float s = g / (1.f + __expf(-g));
        if (!(threadIdx.x & 1))
            out[(size_t)row * HID + (col >> 1)] = __float2bfloat16(s * v);
    }
};

// ------------- flash attention, analytic ALiBi + causal, fixed-shift softmax
__global__ __launch_bounds__(256, 3)
void attn_flash(const bf16* __restrict__ qkv, const bf16* __restrict__ Vt,
                bf16* __restrict__ O) {
    const int bh = blockIdx.x;
    const int qt = gridDim.y - 1 - blockIdx.y;   // heaviest blocks dispatch first
    const int b = bh >> 4, h = bh & 15;
    const int tid = threadIdx.x, wave = tid >> 6, lane = tid & 63;
    const int lo = lane & 15, hi = lane >> 4;
    __shared__ __align__(16) bf16 sQ[64 * 64];
    __shared__ __align__(16) bf16 sK[2][64 * 64];
    __shared__ __align__(16) bf16 sV[2][64 * 64];
    __shared__ __align__(16) bf16 sP[4][16 * 64];

    const float LOG2E = 1.44269504088896340736f;
    const float slope2 = exp2f(-0.5f * (float)(h + 1)) * LOG2E;  // log2-domain slope
    const float qscale = 0.125f * LOG2E;
    const float SHIFT = 34.0f;   // fixed softmax shift (log2); exact by invariance
    const int q0 = qt * 64;
    const bf16* Qb = qkv + (size_t)b * LSEQ * QLD + h * DH;       // q slice
    const bf16* Kb = Qb + DM;                                      // k slice
    const bf16* Vb = Vt + (size_t)bh * DH * LSEQ;

    const int s0 = wave * 2, s1 = wave * 2 + 1;
    auto stageKV = [&](int kt, int buf) {
        load_lds16(Kb + (size_t)(kt * 64 + s0 * 8 + (lane >> 3)) * QLD + (lane & 7) * 8, &sK[buf][s0 * 512]);
        load_lds16(Kb + (size_t)(kt * 64 + s1 * 8 + (lane >> 3)) * QLD + (lane & 7) * 8, &sK[buf][s1 * 512]);
        load_lds16(Vb + (size_t)(s0 * 8 + (lane >> 3)) * LSEQ + kt * 64 + (lane & 7) * 8, &sV[buf][s0 * 512]);
        load_lds16(Vb + (size_t)(s1 * 8 + (lane >> 3)) * LSEQ + kt * 64 + (lane & 7) * 8, &sV[buf][s1 * 512]);
    };

#pragma unroll
    for (int i = 0; i < 2; ++i) {
        const int s = wave * 2 + i;
        load_lds16(Qb + (size_t)(q0 + s * 8 + (lane >> 3)) * QLD + (lane & 7) * 8, &sQ[s * 512]);
    }
    __syncthreads();
    bf16x8 aq0 = *(const bf16x8*)&sQ[(wave * 16 + lo) * 64 + hi * 8];
    bf16x8 aq1 = *(const bf16x8*)&sQ[(wave * 16 + lo) * 64 + 32 + hi * 8];

    bf16x8 vone;
#pragma unroll
    for (int t = 0; t < 8; t++) vone[t] = (__bf16)1.0f;

    f32x4 accO[4];
#pragma unroll
    for (int j = 0; j < 4; j++) accO[j] = (f32x4){0.f, 0.f, 0.f, 0.f};
    f32x4 accL = (f32x4){0.f, 0.f, 0.f, 0.f};
    const int irow0 = q0 + wave * 16 + hi * 4;

    float cbase[4];
#pragma unroll
    for (int r = 0; r < 4; r++) cbase[r] = slope2 * (float)(lo - (irow0 + r)) - SHIFT;
    const float jadd1 = slope2 * 16.f;
    const float kadd = slope2 * 64.f;

    stageKV(0, 0);
    for (int kt = 0; kt <= qt; ++kt) {
        const int bc = kt & 1, bn = bc ^ 1;
        if (kt < qt) {
            stageKV(kt + 1, bn);
            asm volatile("s_waitcnt vmcnt(4)" ::: "memory");
        } else {
            asm volatile("s_waitcnt vmcnt(0)" ::: "memory");
        }
        asm volatile("s_barrier" ::: "memory");   // B1: tile kt visible

        const bool diag = (kt == qt);
#pragma unroll
        for (int j = 0; j < 4; j++) {
            bf16x8 bk0 = *(const bf16x8*)&sK[bc][(j * 16 + lo) * 64 + hi * 8];
            bf16x8 bk1 = *(const bf16x8*)&sK[bc][(j * 16 + lo) * 64 + 32 + hi * 8];
            f32x4 z = (f32x4){0.f, 0.f, 0.f, 0.f};
            z = __builtin_amdgcn_mfma_f32_16x16x32_bf16(aq0, bk0, z, 0, 0, 0);
            z = __builtin_amdgcn_mfma_f32_16x16x32_bf16(aq1, bk1, z, 0, 0, 0);
            const float cj = (float)j * jadd1;
            if (diag) {
                const int jg = kt * 64 + j * 16 + lo;
#pragma unroll
                for (int r = 0; r < 4; r++) {
                    const float pv = (jg > irow0 + r) ? 0.f
                        : exp2f(fmaf(z[r], qscale, cbase[r] + cj));
                    sP[wave][(hi * 4 + r) * 64 + j * 16 + lo] = __float2bfloat16(pv);
                }
            } else {
#pragma unroll
                for (int r = 0; r < 4; r++) {
                    const float pv = exp2f(fmaf(z[r], qscale, cbase[r] + cj));
                    sP[wave][(hi * 4 + r) * 64 + j * 16 + lo] = __float2bfloat16(pv);
                }
            }
        }
#pragma unroll
        for (int r = 0; r < 4; r++) cbase[r] += kadd;
        bf16x8 ap0 = *(const bf16x8*)&sP[wave][lo * 64 + hi * 8];
        bf16x8 ap1 = *(const bf16x8*)&sP[wave][lo * 64 + 32 + hi * 8];
        accL = __builtin_amdgcn_mfma_f32_16x16x32_bf16(ap0, vone, accL, 0, 0, 0);
        accL = __builtin_amdgcn_mfma_f32_16x16x32_bf16(ap1, vone, accL, 0, 0, 0);
#pragma unroll
        for (int j = 0; j < 4; j++) {
            bf16x8 bv0 = *(const bf16x8*)&sV[bc][(j * 16 + lo) * 64 + hi * 8];
            bf16x8 bv1 = *(const bf16x8*)&sV[bc][(j * 16 + lo) * 64 + 32 + hi * 8];
            accO[j] = __builtin_amdgcn_mfma_f32_16x16x32_bf16(ap0, bv0, accO[j], 0, 0, 0);
            accO[j] = __builtin_amdgcn_mfma_f32_16x16x32_bf16(ap1, bv1, accO[j], 0, 0, 0);
        }
        asm volatile("s_barrier" ::: "memory");   // B2: reads of bc done
    }
    bf16* Ob = O + (size_t)b * LSEQ * DM + (size_t)h * DH;
#pragma unroll
    for (int r = 0; r < 4; r++) {
        const float inv = 1.0f / accL[r];
        const int row = q0 + wave * 16 + hi * 4 + r;
#pragma unroll
        for (int j = 0; j < 4; j++)
            Ob[(size_t)row * DM + j * 16 + lo] = __float2bfloat16(accO[j][r] * inv);
    }
}

// ---------------- launch ----------------------------------------------------
extern "C" void kernel_launch(void* const* d_in, const int* in_sizes, int n_in,
                              void* d_out, int out_size, void* d_ws, size_t ws_size,
                              hipStream_t stream) {
    const float* x      = (const float*)d_in[0];
    const float* w_qkv  = (const float*)d_in[3];
    const float* b_qkv  = (const float*)d_in[4];
    const float* w_o    = (const float*)d_in[5];
    const float* b_o    = (const float*)d_in[6];
    const float* scale1 = (const float*)d_in[7];
    const float* scale2 = (const float*)d_in[8];
    const float* w1     = (const float*)d_in[9];
    const float* b1     = (const float*)d_in[10];
    const float* w2     = (const float*)d_in[11];
    const float* b2     = (const float*)d_in[12];
    float* out = (float*)d_out;

    uint8_t* w = (uint8_t*)d_ws;
    size_t off = 0;
    auto take = [&](size_t bytes) { void* p = w + off; off += (bytes + 255) & ~(size_t)255; return p; };
    bf16* xn    = (bf16*)take((size_t)MROWS * DM * 2);
    bf16* wqkvT = (bf16*)take((size_t)3 * DM * DM * 2);
    bf16* woT   = (bf16*)take((size_t)DM * DM * 2);
    bf16* w1T   = (bf16*)take((size_t)2 * HID * DM * 2);
    bf16* w2T   = (bf16*)take((size_t)DM * HID * 2);
    bf16* qkvb  = (bf16*)take((size_t)MROWS * QLD * 2);
    bf16* vt    = (bf16*)take((size_t)MROWS * DM * 2);
    bf16* ao    = (bf16*)take((size_t)MROWS * DM * 2);
    float* x1   = (float*)take((size_t)MROWS * DM * 4);
    bf16* xn2   = (bf16*)take((size_t)MROWS * DM * 2);
    bf16* ffn   = (bf16*)take((size_t)MROWS * HID * 2);
    float* part1 = (float*)take((size_t)3 * MROWS * DM * 4);   // O-proj partials
    float* part2 = (float*)take((size_t)3 * MROWS * DM * 4);   // FFN2 partials

    // weights transpose + first rmsnorm in one dispatch
    transpose_all<<<16384 + MROWS, 256, 0, stream>>>(w_qkv, w_o, w1, w2,
                                                     wqkvT, woT, w1T, w2T,
                                                     x, scale1, xn);

    // QKV: M=4096, N=3072, K=1024  (768 blocks)
    EpiBiasBF16 e1{b_qkv, qkvb, QLD};
    gemm_bt<DM, 24, 1, EpiBiasBF16><<<32 * 24, 256, 0, stream>>>(xn, wqkvT, e1);

    v_transpose<<<dim3(LSEQ / 32, DH / 32, BB * NH), 256, 0, stream>>>(qkvb, vt);
    attn_flash<<<dim3(BB * NH, LSEQ / 64), 256, 0, stream>>>(qkvb, vt, ao);

    // O-proj split-K x3: 768 blocks -> partials, then fused reduce+rmsnorm
    EpiStoreF32 e2{part1};
    gemm_bt<DM, 8, 3, EpiStoreF32><<<3 * 32 * 8, 256, 0, stream>>>(ao, woT, e2);
    oproj_reduce_rmsnorm<<<MROWS, 256, 0, stream>>>(part1, b_o, x, scale2, x1, xn2);

    // FFN1+SwiGLU: M=4096, N=8192, K=1024 — 128x256 tiles (1024 blocks)
    EpiSwiGLU e3{b1, ffn};
    gemm_bt256<DM, 32, EpiSwiGLU><<<32 * 32, 256, 0, stream>>>(xn2, w1T, e3);

    // FFN2 split-K x3: 768 blocks -> partials, then reduce + bias + residual
    EpiStoreF32 e4{part2};
    gemm_bt<HID, 8, 3, EpiStoreF32><<<3 * 32 * 8, 256, 0, stream>>>(ffn, w2T, e4);
    ffn2_reduce<<<MROWS, 256, 0, stream>>>(part2, b2, x1, out);
}

// Round 10
// 674.412 us; speedup vs baseline: 1.0187x; 1.0187x over previous
//
#include <hip/hip_runtime.h>
#include <hip/hip_bf16.h>
#include <stdint.h>

typedef __hip_bfloat16 bf16;
typedef __bf16 bf16x8 __attribute__((ext_vector_type(8)));
typedef float f32x4 __attribute__((ext_vector_type(4)));

#define DM   1024
#define LSEQ 2048
#define NH   16
#define DH   64
#define BB   2
#define HID  4096
#define MROWS (BB*LSEQ)   // 4096
#define QLD  (3*DM)       // qkv buffer row stride

__device__ __forceinline__ void load_lds16(const void* g, void* l) {
    __builtin_amdgcn_global_load_lds(
        (const __attribute__((address_space(1))) unsigned int*)g,
        (__attribute__((address_space(3))) unsigned int*)l, 16, 0, 0);
}

union BF4 { ushort4 u; bf16 h[4]; };
__device__ __forceinline__ float4 bf4_to_f4(const bf16* p) {
    BF4 t; t.u = *(const ushort4*)p;
    return make_float4(__bfloat162float(t.h[0]), __bfloat162float(t.h[1]),
                       __bfloat162float(t.h[2]), __bfloat162float(t.h[3]));
}

// ------------- weight transposes (fp32 [R,C] -> bf16 [C,R]) + rmsnorm(x) ----
// w1 uses interleaved dest rows: feature f -> row 2f (x_proj), 2f+1 (gate).
// Tail blocks (bid>=16384) do rmsnorm_cast of x -> xn (independent work).
__global__ __launch_bounds__(256)
void transpose_all(const float* __restrict__ wqkv, const float* __restrict__ wo,
                   const float* __restrict__ w1, const float* __restrict__ w2,
                   bf16* __restrict__ wqkvT, bf16* __restrict__ woT,
                   bf16* __restrict__ w1T, bf16* __restrict__ w2T,
                   const float* __restrict__ x, const float* __restrict__ scale1,
                   bf16* __restrict__ xn) {
    int bid = blockIdx.x;
    if (bid >= 16384) {   // ---- rmsnorm rows ----
        const int row = bid - 16384, tid = threadIdx.x;
        const float4 v = ((const float4*)(x + (size_t)row * DM))[tid];
        float ss = v.x * v.x + v.y * v.y + v.z * v.z + v.w * v.w;
#pragma unroll
        for (int off = 32; off >= 1; off >>= 1) ss += __shfl_xor(ss, off);
        __shared__ float part[4];
        if ((tid & 63) == 0) part[tid >> 6] = ss;
        __syncthreads();
        const float tot = part[0] + part[1] + part[2] + part[3];
        const float rs = rsqrtf(tot * (1.0f / DM) + 1e-8f);
        const float4 s = ((const float4*)scale1)[tid];
        union { bf16 h[4]; uint2 u; } pk;
        pk.h[0] = __float2bfloat16(v.x * rs * s.x);
        pk.h[1] = __float2bfloat16(v.y * rs * s.y);
        pk.h[2] = __float2bfloat16(v.z * rs * s.z);
        pk.h[3] = __float2bfloat16(v.w * rs * s.w);
        ((uint2*)(xn + (size_t)row * DM))[tid] = pk.u;
        return;
    }
    const float* src; bf16* dst; int R, C, bx, by; bool inter = false;
    if (bid < 3072)       { src = wqkv; dst = wqkvT; R = 1024; C = 3072; bx = bid % 96;  by = bid / 96; }
    else if (bid < 4096)  { bid -= 3072;  src = wo; dst = woT;  R = 1024; C = 1024; bx = bid % 32;  by = bid / 32; }
    else if (bid < 12288) { bid -= 4096;  src = w1; dst = w1T;  R = 1024; C = 8192; bx = bid % 256; by = bid / 256; inter = true; }
    else                  { bid -= 12288; src = w2; dst = w2T;  R = 4096; C = 1024; bx = bid % 32;  by = bid / 32; }
    __shared__ float tile[32][33];
    const int c0 = bx * 32, r0 = by * 32;
    const int tx = threadIdx.x & 31, ty = threadIdx.x >> 5;
#pragma unroll
    for (int i = 0; i < 32; i += 8)
        tile[ty + i][tx] = src[(size_t)(r0 + ty + i) * C + c0 + tx];
    __syncthreads();
#pragma unroll
    for (int i = 0; i < 32; i += 8) {
        const int c = c0 + ty + i;
        const int drow = inter ? ((c < HID) ? 2 * c : 2 * (c - HID) + 1) : c;
        dst[(size_t)drow * R + r0 + tx] = __float2bfloat16(tile[tx][ty + i]);
    }
}

// ------------- V slice of qkv -> vt [BH, DH, L] -----------------------------
__global__ __launch_bounds__(256)
void v_transpose(const bf16* __restrict__ qkv, bf16* __restrict__ vt) {
    const int bh = blockIdx.z, b = bh >> 4, h = bh & 15;
    const int l0 = blockIdx.x * 32, d0 = blockIdx.y * 32;
    __shared__ bf16 tile[32][33];
    const int tx = threadIdx.x & 31, ty = threadIdx.x >> 5;
#pragma unroll
    for (int i = 0; i < 32; i += 8)
        tile[ty + i][tx] = qkv[((size_t)b * LSEQ + l0 + ty + i) * QLD + 2 * DM + h * DH + d0 + tx];
    __syncthreads();
#pragma unroll
    for (int i = 0; i < 32; i += 8)
        vt[((size_t)bh * DH + d0 + ty + i) * LSEQ + l0 + tx] = tile[tx][ty + i];
}

// ------- O-proj reduce: x1 = sum3 bf16 partials + b_o + x ; xn2 = rmsnorm ---
__global__ __launch_bounds__(256)
void oproj_reduce_rmsnorm(const bf16* __restrict__ part, const float* __restrict__ bias,
                          const float* __restrict__ res, const float* __restrict__ scale,
                          float* __restrict__ x1, bf16* __restrict__ xn2) {
    const int row = blockIdx.x, tid = threadIdx.x;
    const float4 p0 = bf4_to_f4(part + ((size_t)row) * DM + tid * 4);
    const float4 p1 = bf4_to_f4(part + ((size_t)MROWS + row) * DM + tid * 4);
    const float4 p2 = bf4_to_f4(part + ((size_t)2 * MROWS + row) * DM + tid * 4);
    const float4 bb = ((const float4*)bias)[tid];
    const float4 rr = ((const float4*)(res + (size_t)row * DM))[tid];
    float4 v;
    v.x = p0.x + p1.x + p2.x + bb.x + rr.x;
    v.y = p0.y + p1.y + p2.y + bb.y + rr.y;
    v.z = p0.z + p1.z + p2.z + bb.z + rr.z;
    v.w = p0.w + p1.w + p2.w + bb.w + rr.w;
    ((float4*)(x1 + (size_t)row * DM))[tid] = v;
    float ss = v.x * v.x + v.y * v.y + v.z * v.z + v.w * v.w;
#pragma unroll
    for (int off = 32; off >= 1; off >>= 1) ss += __shfl_xor(ss, off);
    __shared__ float partl[4];
    if ((tid & 63) == 0) partl[tid >> 6] = ss;
    __syncthreads();
    const float tot = partl[0] + partl[1] + partl[2] + partl[3];
    const float rs = rsqrtf(tot * (1.0f / DM) + 1e-8f);
    const float4 s = ((const float4*)scale)[tid];
    union { bf16 h[4]; uint2 u; } pk;
    pk.h[0] = __float2bfloat16(v.x * rs * s.x);
    pk.h[1] = __float2bfloat16(v.y * rs * s.y);
    pk.h[2] = __float2bfloat16(v.z * rs * s.z);
    pk.h[3] = __float2bfloat16(v.w * rs * s.w);
    ((uint2*)(xn2 + (size_t)row * DM))[tid] = pk.u;
}

// ------- FFN2 reduce: out = sum3 bf16 partials + b2 + x1 --------------------
__global__ __launch_bounds__(256)
void ffn2_reduce(const bf16* __restrict__ part, const float* __restrict__ b2,
                 const float* __restrict__ x1, float* __restrict__ out) {
    const int g = blockIdx.x * 256 + threadIdx.x;   // float4 index over 4096x1024
    const int c4 = g & 255;
    const float4 p0 = bf4_to_f4(part + (size_t)g * 4);
    const float4 p1 = bf4_to_f4(part + (size_t)MROWS * DM + (size_t)g * 4);
    const float4 p2 = bf4_to_f4(part + (size_t)2 * MROWS * DM + (size_t)g * 4);
    const float4 bb = ((const float4*)b2)[c4];
    const float4 rr = ((const float4*)x1)[g];
    float4 v;
    v.x = p0.x + p1.x + p2.x + bb.x + rr.x;
    v.y = p0.y + p1.y + p2.y + bb.y + rr.y;
    v.z = p0.z + p1.z + p2.z + bb.z + rr.z;
    v.w = p0.w + p1.w + p2.w + bb.w + rr.w;
    ((float4*)out)[g] = v;
}

// ------------- bf16 GEMM 128x128: C[M,N] = A[M,K] @ Bt[N,K]^T ---------------
// Triple-buffered LDS, one raw s_barrier per K-iter, s_waitcnt vmcnt(4).
// Optional split-K (S>1). XCD panel swizzle for B L2 residency.
template <int KDIM, int NN, int S, typename Epi>
__global__ __launch_bounds__(256, 3)
void gemm_bt(const bf16* __restrict__ A, const bf16* __restrict__ Bt, Epi epi) {
    __shared__ __align__(16) bf16 sA[3][128 * 32];
    __shared__ __align__(16) bf16 sB[3][128 * 32];
    constexpr int NPX = NN / 8;            // n-tiles per XCD panel
    constexpr int MBNB = (MROWS / 128) * NN;
    const int bid = blockIdx.x;
    const int sk = (S > 1) ? bid / MBNB : 0;
    const int ib = (S > 1) ? bid % MBNB : bid;
    const int xcd = ib & 7, loc = ib >> 3;
    const int nb = xcd * NPX + (loc % NPX), mb = loc / NPX;
    const int m0 = mb * 128, n0 = nb * 128;
    const int tid = threadIdx.x;
    const int wave = tid >> 6, lane = tid & 63;
    const int lo = lane & 15, hi = lane >> 4;
    const int wm = wave & 1, wn = wave >> 1;
    const int rowA = lane >> 2, cc = (lane & 3) * 8;
    const int slot0 = wave * 2, slot1 = wave * 2 + 1;

    const bf16* Ag0 = A + (size_t)(m0 + slot0 * 16 + rowA) * KDIM + cc;
    const bf16* Ag1 = A + (size_t)(m0 + slot1 * 16 + rowA) * KDIM + cc;
    const bf16* Bg0 = Bt + (size_t)(n0 + slot0 * 16 + rowA) * KDIM + cc;
    const bf16* Bg1 = Bt + (size_t)(n0 + slot1 * 16 + rowA) * KDIM + cc;

    auto stage = [&](int kt, int buf) {
        const int k0 = kt * 32;
        load_lds16(Ag0 + k0, &sA[buf][slot0 * 512]);
        load_lds16(Ag1 + k0, &sA[buf][slot1 * 512]);
        load_lds16(Bg0 + k0, &sB[buf][slot0 * 512]);
        load_lds16(Bg1 + k0, &sB[buf][slot1 * 512]);
    };

    f32x4 acc[4][4];
#pragma unroll
    for (int i = 0; i < 4; i++)
#pragma unroll
        for (int j = 0; j < 4; j++) acc[i][j] = (f32x4){0.f, 0.f, 0.f, 0.f};

    constexpr int NK = KDIM / 32;
    const int kt0 = (S > 1) ? (sk * NK) / S : 0;
    const int kt1 = (S > 1) ? ((sk + 1) * NK) / S : NK;
    stage(kt0, 0);
    int bc = 0;
    for (int kt = kt0; kt < kt1; ++kt) {
        const int bn = (bc == 2) ? 0 : bc + 1;
        if (kt + 1 < kt1) {
            stage(kt + 1, bn);
            asm volatile("s_waitcnt vmcnt(4)" ::: "memory");  // drain tile kt only
        } else {
            asm volatile("s_waitcnt vmcnt(0)" ::: "memory");
        }
        asm volatile("s_barrier" ::: "memory");               // raw: no vmcnt(0) drain
        const bf16* cA = sA[bc];
        const bf16* cB = sB[bc];
        bf16x8 a[4], b[4];
#pragma unroll
        for (int i = 0; i < 4; i++)
            a[i] = *(const bf16x8*)&cA[(wm * 64 + i * 16 + lo) * 32 + hi * 8];
#pragma unroll
        for (int j = 0; j < 4; j++)
            b[j] = *(const bf16x8*)&cB[(wn * 64 + j * 16 + lo) * 32 + hi * 8];
#pragma unroll
        for (int i = 0; i < 4; i++)
#pragma unroll
            for (int j = 0; j < 4; j++)
                acc[i][j] = __builtin_amdgcn_mfma_f32_16x16x32_bf16(a[i], b[j], acc[i][j], 0, 0, 0);
        bc = bn;
    }
    const int rbase = sk * MROWS + m0;
#pragma unroll
    for (int i = 0; i < 4; i++) {
        const int row = rbase + wm * 64 + i * 16 + hi * 4;
#pragma unroll
        for (int j = 0; j < 4; j++) {
            const int col = n0 + wn * 64 + j * 16 + lo;
#pragma unroll
            for (int r = 0; r < 4; r++) epi(row + r, col, acc[i][j][r]);
        }
    }
}

// Epilogues
struct EpiBiasBF16 {      // out bf16 = val + bias[col]
    const float* bias; bf16* out; int ldc;
    __device__ void operator()(int row, int col, float val) const {
        out[(size_t)row * ldc + col] = __float2bfloat16(val + bias[col]);
    }
};
struct EpiStoreBF16 {     // bf16 partial store (split-K)
    bf16* out;
    __device__ void operator()(int row, int col, float val) const {
        out[(size_t)row * DM + col] = __float2bfloat16(val);
    }
};
struct EpiSwiGLU {        // interleaved cols: even=x_proj feature col/2, odd=gate
    const float* b1; bf16* out;
    __device__ void operator()(int row, int col, float val) const {
        const int orig = (col >> 1) + ((col & 1) ? HID : 0);
        const float v = val + b1[orig];
        const float other = __shfl_xor(v, 1);
        const float g = other;
        const float s = g / (1.f + __expf(-g));
        if (!(threadIdx.x & 1))
            out[(size_t)row * HID + (col >> 1)] = __float2bfloat16(s * v);
    }
};

// ------------- flash attention, analytic ALiBi + causal, fixed-shift softmax
// Double-buffered K/V staging, two raw s_barriers per kt, vmcnt(4) prefetch.
__global__ __launch_bounds__(256, 3)
void attn_flash(const bf16* __restrict__ qkv, const bf16* __restrict__ Vt,
                bf16* __restrict__ O) {
    const int bh = blockIdx.x;
    const int qt = gridDim.y - 1 - blockIdx.y;   // heaviest blocks dispatch first
    const int b = bh >> 4, h = bh & 15;
    const int tid = threadIdx.x, wave = tid >> 6, lane = tid & 63;
    const int lo = lane & 15, hi = lane >> 4;
    __shared__ __align__(16) bf16 sQ[64 * 64];
    __shared__ __align__(16) bf16 sK[2][64 * 64];
    __shared__ __align__(16) bf16 sV[2][64 * 64];
    __shared__ __align__(16) bf16 sP[4][16 * 64];

    const float LOG2E = 1.44269504088896340736f;
    const float slope2 = exp2f(-0.5f * (float)(h + 1)) * LOG2E;  // log2-domain slope
    const float qscale = 0.125f * LOG2E;
    const float SHIFT = 34.0f;   // fixed softmax shift (log2); exact by invariance
    const int q0 = qt * 64;
    const bf16* Qb = qkv + (size_t)b * LSEQ * QLD + h * DH;       // q slice
    const bf16* Kb = Qb + DM;                                      // k slice
    const bf16* Vb = Vt + (size_t)bh * DH * LSEQ;

    const int s0 = wave * 2, s1 = wave * 2 + 1;
    auto stageKV = [&](int kt, int buf) {
        load_lds16(Kb + (size_t)(kt * 64 + s0 * 8 + (lane >> 3)) * QLD + (lane & 7) * 8, &sK[buf][s0 * 512]);
        load_lds16(Kb + (size_t)(kt * 64 + s1 * 8 + (lane >> 3)) * QLD + (lane & 7) * 8, &sK[buf][s1 * 512]);
        load_lds16(Vb + (size_t)(s0 * 8 + (lane >> 3)) * LSEQ + kt * 64 + (lane & 7) * 8, &sV[buf][s0 * 512]);
        load_lds16(Vb + (size_t)(s1 * 8 + (lane >> 3)) * LSEQ + kt * 64 + (lane & 7) * 8, &sV[buf][s1 * 512]);
    };

#pragma unroll
    for (int i = 0; i < 2; ++i) {
        const int s = wave * 2 + i;
        load_lds16(Qb + (size_t)(q0 + s * 8 + (lane >> 3)) * QLD + (lane & 7) * 8, &sQ[s * 512]);
    }
    __syncthreads();
    bf16x8 aq0 = *(const bf16x8*)&sQ[(wave * 16 + lo) * 64 + hi * 8];
    bf16x8 aq1 = *(const bf16x8*)&sQ[(wave * 16 + lo) * 64 + 32 + hi * 8];

    bf16x8 vone;
#pragma unroll
    for (int t = 0; t < 8; t++) vone[t] = (__bf16)1.0f;

    f32x4 accO[4];
#pragma unroll
    for (int j = 0; j < 4; j++) accO[j] = (f32x4){0.f, 0.f, 0.f, 0.f};
    f32x4 accL = (f32x4){0.f, 0.f, 0.f, 0.f};
    const int irow0 = q0 + wave * 16 + hi * 4;

    float cbase[4];
#pragma unroll
    for (int r = 0; r < 4; r++) cbase[r] = slope2 * (float)(lo - (irow0 + r)) - SHIFT;
    const float jadd1 = slope2 * 16.f;
    const float kadd = slope2 * 64.f;

    stageKV(0, 0);
    for (int kt = 0; kt <= qt; ++kt) {
        const int bc = kt & 1, bn = bc ^ 1;
        if (kt < qt) {
            stageKV(kt + 1, bn);
            asm volatile("s_waitcnt vmcnt(4)" ::: "memory");
        } else {
            asm volatile("s_waitcnt vmcnt(0)" ::: "memory");
        }
        asm volatile("s_barrier" ::: "memory");   // B1: tile kt visible

        const bool diag = (kt == qt);
#pragma unroll
        for (int j = 0; j < 4; j++) {
            bf16x8 bk0 = *(const bf16x8*)&sK[bc][(j * 16 + lo) * 64 + hi * 8];
            bf16x8 bk1 = *(const bf16x8*)&sK[bc][(j * 16 + lo) * 64 + 32 + hi * 8];
            f32x4 z = (f32x4){0.f, 0.f, 0.f, 0.f};
            z = __builtin_amdgcn_mfma_f32_16x16x32_bf16(aq0, bk0, z, 0, 0, 0);
            z = __builtin_amdgcn_mfma_f32_16x16x32_bf16(aq1, bk1, z, 0, 0, 0);
            const float cj = (float)j * jadd1;
            if (diag) {
                const int jg = kt * 64 + j * 16 + lo;
#pragma unroll
                for (int r = 0; r < 4; r++) {
                    const float pv = (jg > irow0 + r) ? 0.f
                        : exp2f(fmaf(z[r], qscale, cbase[r] + cj));
                    sP[wave][(hi * 4 + r) * 64 + j * 16 + lo] = __float2bfloat16(pv);
                }
            } else {
#pragma unroll
                for (int r = 0; r < 4; r++) {
                    const float pv = exp2f(fmaf(z[r], qscale, cbase[r] + cj));
                    sP[wave][(hi * 4 + r) * 64 + j * 16 + lo] = __float2bfloat16(pv);
                }
            }
        }
#pragma unroll
        for (int r = 0; r < 4; r++) cbase[r] += kadd;
        bf16x8 ap0 = *(const bf16x8*)&sP[wave][lo * 64 + hi * 8];
        bf16x8 ap1 = *(const bf16x8*)&sP[wave][lo * 64 + 32 + hi * 8];
        accL = __builtin_amdgcn_mfma_f32_16x16x32_bf16(ap0, vone, accL, 0, 0, 0);
        accL = __builtin_amdgcn_mfma_f32_16x16x32_bf16(ap1, vone, accL, 0, 0, 0);
#pragma unroll
        for (int j = 0; j < 4; j++) {
            bf16x8 bv0 = *(const bf16x8*)&sV[bc][(j * 16 + lo) * 64 + hi * 8];
            bf16x8 bv1 = *(const bf16x8*)&sV[bc][(j * 16 + lo) * 64 + 32 + hi * 8];
            accO[j] = __builtin_amdgcn_mfma_f32_16x16x32_bf16(ap0, bv0, accO[j], 0, 0, 0);
            accO[j] = __builtin_amdgcn_mfma_f32_16x16x32_bf16(ap1, bv1, accO[j], 0, 0, 0);
        }
        asm volatile("s_barrier" ::: "memory");   // B2: reads of bc done
    }
    bf16* Ob = O + (size_t)b * LSEQ * DM + (size_t)h * DH;
#pragma unroll
    for (int r = 0; r < 4; r++) {
        const float inv = 1.0f / accL[r];
        const int row = q0 + wave * 16 + hi * 4 + r;
#pragma unroll
        for (int j = 0; j < 4; j++)
            Ob[(size_t)row * DM + j * 16 + lo] = __float2bfloat16(accO[j][r] * inv);
    }
}

// ---------------- launch ----------------------------------------------------
extern "C" void kernel_launch(void* const* d_in, const int* in_sizes, int n_in,
                              void* d_out, int out_size, void* d_ws, size_t ws_size,
                              hipStream_t stream) {
    const float* x      = (const float*)d_in[0];
    const float* w_qkv  = (const float*)d_in[3];
    const float* b_qkv  = (const float*)d_in[4];
    const float* w_o    = (const float*)d_in[5];
    const float* b_o    = (const float*)d_in[6];
    const float* scale1 = (const float*)d_in[7];
    const float* scale2 = (const float*)d_in[8];
    const float* w1     = (const float*)d_in[9];
    const float* b1     = (const float*)d_in[10];
    const float* w2     = (const float*)d_in[11];
    const float* b2     = (const float*)d_in[12];
    float* out = (float*)d_out;

    uint8_t* w = (uint8_t*)d_ws;
    size_t off = 0;
    auto take = [&](size_t bytes) { void* p = w + off; off += (bytes + 255) & ~(size_t)255; return p; };
    bf16* xn    = (bf16*)take((size_t)MROWS * DM * 2);
    bf16* wqkvT = (bf16*)take((size_t)3 * DM * DM * 2);
    bf16* woT   = (bf16*)take((size_t)DM * DM * 2);
    bf16* w1T   = (bf16*)take((size_t)2 * HID * DM * 2);
    bf16* w2T   = (bf16*)take((size_t)DM * HID * 2);
    bf16* qkvb  = (bf16*)take((size_t)MROWS * QLD * 2);
    bf16* vt    = (bf16*)take((size_t)MROWS * DM * 2);
    bf16* ao    = (bf16*)take((size_t)MROWS * DM * 2);
    float* x1   = (float*)take((size_t)MROWS * DM * 4);
    bf16* xn2   = (bf16*)take((size_t)MROWS * DM * 2);
    bf16* ffn   = (bf16*)take((size_t)MROWS * HID * 2);
    bf16* part1 = (bf16*)take((size_t)3 * MROWS * DM * 2);   // O-proj partials (bf16)
    bf16* part2 = (bf16*)take((size_t)3 * MROWS * DM * 2);   // FFN2 partials (bf16)

    // weights transpose + first rmsnorm in one dispatch
    transpose_all<<<16384 + MROWS, 256, 0, stream>>>(w_qkv, w_o, w1, w2,
                                                     wqkvT, woT, w1T, w2T,
                                                     x, scale1, xn);

    // QKV: M=4096, N=3072, K=1024  (768 blocks)
    EpiBiasBF16 e1{b_qkv, qkvb, QLD};
    gemm_bt<DM, 24, 1, EpiBiasBF16><<<32 * 24, 256, 0, stream>>>(xn, wqkvT, e1);

    v_transpose<<<dim3(LSEQ / 32, DH / 32, BB * NH), 256, 0, stream>>>(qkvb, vt);
    attn_flash<<<dim3(BB * NH, LSEQ / 64), 256, 0, stream>>>(qkvb, vt, ao);

    // O-proj split-K x3: 768 blocks -> bf16 partials, then fused reduce+rmsnorm
    EpiStoreBF16 e2{part1};
    gemm_bt<DM, 8, 3, EpiStoreBF16><<<3 * 32 * 8, 256, 0, stream>>>(ao, woT, e2);
    oproj_reduce_rmsnorm<<<MROWS, 256, 0, stream>>>(part1, b_o, x, scale2, x1, xn2);

    // FFN1+SwiGLU: M=4096, N=8192, K=1024  (2048 blocks, 128x128)
    EpiSwiGLU e3{b1, ffn};
    gemm_bt<DM, 64, 1, EpiSwiGLU><<<32 * 64, 256, 0, stream>>>(xn2, w1T, e3);

    // FFN2 split-K x3: 768 blocks -> bf16 partials, then reduce + bias + resid
    EpiStoreBF16 e4{part2};
    gemm_bt<HID, 8, 3, EpiStoreBF16><<<3 * 32 * 8, 256, 0, stream>>>(ffn, w2T, e4);
    ffn2_reduce<<<MROWS, 256, 0, stream>>>(part2, b2, x1, out);
}

// Round 12
// 671.303 us; speedup vs baseline: 1.0234x; 1.0046x over previous
//
#include <hip/hip_runtime.h>
#include <hip/hip_bf16.h>
#include <stdint.h>

typedef __hip_bfloat16 bf16;
typedef __bf16 bf16x8 __attribute__((ext_vector_type(8)));
typedef float f32x4 __attribute__((ext_vector_type(4)));

#define DM   1024
#define LSEQ 2048
#define NH   16
#define DH   64
#define BB   2
#define HID  4096
#define MROWS (BB*LSEQ)   // 4096
#define QLD  (3*DM)       // qkv buffer row stride

__device__ __forceinline__ void load_lds16(const void* g, void* l) {
    __builtin_amdgcn_global_load_lds(
        (const __attribute__((address_space(1))) unsigned int*)g,
        (__attribute__((address_space(3))) unsigned int*)l, 16, 0, 0);
}

union BF4 { ushort4 u; bf16 h[4]; };
__device__ __forceinline__ float4 bf4_to_f4(const bf16* p) {
    BF4 t; t.u = *(const ushort4*)p;
    return make_float4(__bfloat162float(t.h[0]), __bfloat162float(t.h[1]),
                       __bfloat162float(t.h[2]), __bfloat162float(t.h[3]));
}

// ------------- weight transposes (fp32 [R,C] -> bf16 [C,R]) + rmsnorm(x) ----
// w1 uses interleaved dest rows: feature f -> row 2f (x_proj), 2f+1 (gate).
// Tail blocks (bid>=16384) do rmsnorm_cast of x -> xn (independent work).
__global__ __launch_bounds__(256)
void transpose_all(const float* __restrict__ wqkv, const float* __restrict__ wo,
                   const float* __restrict__ w1, const float* __restrict__ w2,
                   bf16* __restrict__ wqkvT, bf16* __restrict__ woT,
                   bf16* __restrict__ w1T, bf16* __restrict__ w2T,
                   const float* __restrict__ x, const float* __restrict__ scale1,
                   bf16* __restrict__ xn) {
    int bid = blockIdx.x;
    if (bid >= 16384) {   // ---- rmsnorm rows ----
        const int row = bid - 16384, tid = threadIdx.x;
        const float4 v = ((const float4*)(x + (size_t)row * DM))[tid];
        float ss = v.x * v.x + v.y * v.y + v.z * v.z + v.w * v.w;
#pragma unroll
        for (int off = 32; off >= 1; off >>= 1) ss += __shfl_xor(ss, off);
        __shared__ float part[4];
        if ((tid & 63) == 0) part[tid >> 6] = ss;
        __syncthreads();
        const float tot = part[0] + part[1] + part[2] + part[3];
        const float rs = rsqrtf(tot * (1.0f / DM) + 1e-8f);
        const float4 s = ((const float4*)scale1)[tid];
        union { bf16 h[4]; uint2 u; } pk;
        pk.h[0] = __float2bfloat16(v.x * rs * s.x);
        pk.h[1] = __float2bfloat16(v.y * rs * s.y);
        pk.h[2] = __float2bfloat16(v.z * rs * s.z);
        pk.h[3] = __float2bfloat16(v.w * rs * s.w);
        ((uint2*)(xn + (size_t)row * DM))[tid] = pk.u;
        return;
    }
    const float* src; bf16* dst; int R, C, bx, by; bool inter = false;
    if (bid < 3072)       { src = wqkv; dst = wqkvT; R = 1024; C = 3072; bx = bid % 96;  by = bid / 96; }
    else if (bid < 4096)  { bid -= 3072;  src = wo; dst = woT;  R = 1024; C = 1024; bx = bid % 32;  by = bid / 32; }
    else if (bid < 12288) { bid -= 4096;  src = w1; dst = w1T;  R = 1024; C = 8192; bx = bid % 256; by = bid / 256; inter = true; }
    else                  { bid -= 12288; src = w2; dst = w2T;  R = 4096; C = 1024; bx = bid % 32;  by = bid / 32; }
    __shared__ float tile[32][33];
    const int c0 = bx * 32, r0 = by * 32;
    const int tx = threadIdx.x & 31, ty = threadIdx.x >> 5;
#pragma unroll
    for (int i = 0; i < 32; i += 8)
        tile[ty + i][tx] = src[(size_t)(r0 + ty + i) * C + c0 + tx];
    __syncthreads();
#pragma unroll
    for (int i = 0; i < 32; i += 8) {
        const int c = c0 + ty + i;
        const int drow = inter ? ((c < HID) ? 2 * c : 2 * (c - HID) + 1) : c;
        dst[(size_t)drow * R + r0 + tx] = __float2bfloat16(tile[tx][ty + i]);
    }
}

// ------------- V slice of qkv -> vt [BH, DH, L] -----------------------------
__global__ __launch_bounds__(256)
void v_transpose(const bf16* __restrict__ qkv, bf16* __restrict__ vt) {
    const int bh = blockIdx.z, b = bh >> 4, h = bh & 15;
    const int l0 = blockIdx.x * 32, d0 = blockIdx.y * 32;
    __shared__ bf16 tile[32][33];
    const int tx = threadIdx.x & 31, ty = threadIdx.x >> 5;
#pragma unroll
    for (int i = 0; i < 32; i += 8)
        tile[ty + i][tx] = qkv[((size_t)b * LSEQ + l0 + ty + i) * QLD + 2 * DM + h * DH + d0 + tx];
    __syncthreads();
#pragma unroll
    for (int i = 0; i < 32; i += 8)
        vt[((size_t)bh * DH + d0 + ty + i) * LSEQ + l0 + tx] = tile[tx][ty + i];
}

// ------- O-proj reduce: x1 = sum3 bf16 partials + b_o + x ; xn2 = rmsnorm ---
__global__ __launch_bounds__(256)
void oproj_reduce_rmsnorm(const bf16* __restrict__ part, const float* __restrict__ bias,
                          const float* __restrict__ res, const float* __restrict__ scale,
                          float* __restrict__ x1, bf16* __restrict__ xn2) {
    const int row = blockIdx.x, tid = threadIdx.x;
    const float4 p0 = bf4_to_f4(part + ((size_t)row) * DM + tid * 4);
    const float4 p1 = bf4_to_f4(part + ((size_t)MROWS + row) * DM + tid * 4);
    const float4 p2 = bf4_to_f4(part + ((size_t)2 * MROWS + row) * DM + tid * 4);
    const float4 bb = ((const float4*)bias)[tid];
    const float4 rr = ((const float4*)(res + (size_t)row * DM))[tid];
    float4 v;
    v.x = p0.x + p1.x + p2.x + bb.x + rr.x;
    v.y = p0.y + p1.y + p2.y + bb.y + rr.y;
    v.z = p0.z + p1.z + p2.z + bb.z + rr.z;
    v.w = p0.w + p1.w + p2.w + bb.w + rr.w;
    ((float4*)(x1 + (size_t)row * DM))[tid] = v;
    float ss = v.x * v.x + v.y * v.y + v.z * v.z + v.w * v.w;
#pragma unroll
    for (int off = 32; off >= 1; off >>= 1) ss += __shfl_xor(ss, off);
    __shared__ float partl[4];
    if ((tid & 63) == 0) partl[tid >> 6] = ss;
    __syncthreads();
    const float tot = partl[0] + partl[1] + partl[2] + partl[3];
    const float rs = rsqrtf(tot * (1.0f / DM) + 1e-8f);
    const float4 s = ((const float4*)scale)[tid];
    union { bf16 h[4]; uint2 u; } pk;
    pk.h[0] = __float2bfloat16(v.x * rs * s.x);
    pk.h[1] = __float2bfloat16(v.y * rs * s.y);
    pk.h[2] = __float2bfloat16(v.z * rs * s.z);
    pk.h[3] = __float2bfloat16(v.w * rs * s.w);
    ((uint2*)(xn2 + (size_t)row * DM))[tid] = pk.u;
}

// ------- FFN2 reduce: out = sum3 bf16 partials + b2 + x1 --------------------
__global__ __launch_bounds__(256)
void ffn2_reduce(const bf16* __restrict__ part, const float* __restrict__ b2,
                 const float* __restrict__ x1, float* __restrict__ out) {
    const int g = blockIdx.x * 256 + threadIdx.x;   // float4 index over 4096x1024
    const int c4 = g & 255;
    const float4 p0 = bf4_to_f4(part + (size_t)g * 4);
    const float4 p1 = bf4_to_f4(part + (size_t)MROWS * DM + (size_t)g * 4);
    const float4 p2 = bf4_to_f4(part + (size_t)2 * MROWS * DM + (size_t)g * 4);
    const float4 bb = ((const float4*)b2)[c4];
    const float4 rr = ((const float4*)x1)[g];
    float4 v;
    v.x = p0.x + p1.x + p2.x + bb.x + rr.x;
    v.y = p0.y + p1.y + p2.y + bb.y + rr.y;
    v.z = p0.z + p1.z + p2.z + bb.z + rr.z;
    v.w = p0.w + p1.w + p2.w + bb.w + rr.w;
    ((float4*)out)[g] = v;
}

// ------------- bf16 GEMM 128x128: C[M,N] = A[M,K] @ Bt[N,K]^T ---------------
// Triple-buffered LDS, one raw s_barrier per K-iter, PREFETCH DISTANCE 2:
// stage(kt+2) is issued AFTER the barrier (post-barrier, all waves are done
// reading buf (kt-1)%3 == (kt+2)%3, so depth-2 is race-free with 3 buffers).
// Steady state: 8 loads in flight, s_waitcnt vmcnt(4) drains tile kt only ->
// each tile rides ~2 iters (covers HBM latency, L3 is poison-flushed between
// graph replays). Optional split-K (S>1). XCD panel swizzle for B residency.
template <int KDIM, int NN, int S, typename Epi>
__global__ __launch_bounds__(256, 3)
void gemm_bt(const bf16* __restrict__ A, const bf16* __restrict__ Bt, Epi epi) {
    __shared__ __align__(16) bf16 sA[3][128 * 32];
    __shared__ __align__(16) bf16 sB[3][128 * 32];
    constexpr int NPX = NN / 8;            // n-tiles per XCD panel
    constexpr int MBNB = (MROWS / 128) * NN;
    const int bid = blockIdx.x;
    const int sk = (S > 1) ? bid / MBNB : 0;
    const int ib = (S > 1) ? bid % MBNB : bid;
    const int xcd = ib & 7, loc = ib >> 3;
    const int nb = xcd * NPX + (loc % NPX), mb = loc / NPX;
    const int m0 = mb * 128, n0 = nb * 128;
    const int tid = threadIdx.x;
    const int wave = tid >> 6, lane = tid & 63;
    const int lo = lane & 15, hi = lane >> 4;
    const int wm = wave & 1, wn = wave >> 1;
    const int rowA = lane >> 2, cc = (lane & 3) * 8;
    const int slot0 = wave * 2, slot1 = wave * 2 + 1;

    const bf16* Ag0 = A + (size_t)(m0 + slot0 * 16 + rowA) * KDIM + cc;
    const bf16* Ag1 = A + (size_t)(m0 + slot1 * 16 + rowA) * KDIM + cc;
    const bf16* Bg0 = Bt + (size_t)(n0 + slot0 * 16 + rowA) * KDIM + cc;
    const bf16* Bg1 = Bt + (size_t)(n0 + slot1 * 16 + rowA) * KDIM + cc;

    auto stage = [&](int kt, int buf) {
        const int k0 = kt * 32;
        load_lds16(Ag0 + k0, &sA[buf][slot0 * 512]);
        load_lds16(Ag1 + k0, &sA[buf][slot1 * 512]);
        load_lds16(Bg0 + k0, &sB[buf][slot0 * 512]);
        load_lds16(Bg1 + k0, &sB[buf][slot1 * 512]);
    };

    f32x4 acc[4][4];
#pragma unroll
    for (int i = 0; i < 4; i++)
#pragma unroll
        for (int j = 0; j < 4; j++) acc[i][j] = (f32x4){0.f, 0.f, 0.f, 0.f};

    constexpr int NK = KDIM / 32;
    const int kt0 = (S > 1) ? (sk * NK) / S : 0;
    const int kt1 = (S > 1) ? ((sk + 1) * NK) / S : NK;
    stage(kt0, 0);
    if (kt0 + 1 < kt1) stage(kt0 + 1, 1);
    int bc = 0;
    for (int kt = kt0; kt < kt1; ++kt) {
        if (kt + 1 < kt1) {
            asm volatile("s_waitcnt vmcnt(4)" ::: "memory");  // drain tile kt only
        } else {
            asm volatile("s_waitcnt vmcnt(0)" ::: "memory");
        }
        asm volatile("s_barrier" ::: "memory");               // raw: no vmcnt(0) drain
        if (kt + 2 < kt1) {          // depth-2 prefetch into (bc+2)%3 — the buf
            int b2 = bc + 2;         // all waves just finished reading (post-barrier)
            if (b2 >= 3) b2 -= 3;
            stage(kt + 2, b2);
        }
        const bf16* cA = sA[bc];
        const bf16* cB = sB[bc];
        bf16x8 a[4], b[4];
#pragma unroll
        for (int i = 0; i < 4; i++)
            a[i] = *(const bf16x8*)&cA[(wm * 64 + i * 16 + lo) * 32 + hi * 8];
#pragma unroll
        for (int j = 0; j < 4; j++)
            b[j] = *(const bf16x8*)&cB[(wn * 64 + j * 16 + lo) * 32 + hi * 8];
#pragma unroll
        for (int i = 0; i < 4; i++)
#pragma unroll
            for (int j = 0; j < 4; j++)
                acc[i][j] = __builtin_amdgcn_mfma_f32_16x16x32_bf16(a[i], b[j], acc[i][j], 0, 0, 0);
        bc = (bc == 2) ? 0 : bc + 1;
    }
    const int rbase = sk * MROWS + m0;
#pragma unroll
    for (int i = 0; i < 4; i++) {
        const int row = rbase + wm * 64 + i * 16 + hi * 4;
#pragma unroll
        for (int j = 0; j < 4; j++) {
            const int col = n0 + wn * 64 + j * 16 + lo;
#pragma unroll
            for (int r = 0; r < 4; r++) epi(row + r, col, acc[i][j][r]);
        }
    }
}

// Epilogues
struct EpiBiasBF16 {      // out bf16 = val + bias[col]
    const float* bias; bf16* out; int ldc;
    __device__ void operator()(int row, int col, float val) const {
        out[(size_t)row * ldc + col] = __float2bfloat16(val + bias[col]);
    }
};
struct EpiStoreBF16 {     // bf16 partial store (split-K)
    bf16* out;
    __device__ void operator()(int row, int col, float val) const {
        out[(size_t)row * DM + col] = __float2bfloat16(val);
    }
};
struct EpiSwiGLU {        // interleaved cols: even=x_proj feature col/2, odd=gate
    const float* b1; bf16* out;
    __device__ void operator()(int row, int col, float val) const {
        const int orig = (col >> 1) + ((col & 1) ? HID : 0);
        const float v = val + b1[orig];
        const float other = __shfl_xor(v, 1);
        const float g = other;
        const float s = g / (1.f + __expf(-g));
        if (!(threadIdx.x & 1))
            out[(size_t)row * HID + (col >> 1)] = __float2bfloat16(s * v);
    }
};

// ------------- flash attention, analytic ALiBi + causal, fixed-shift softmax
// Double-buffered K/V staging, two raw s_barriers per kt, vmcnt(4) prefetch.
__global__ __launch_bounds__(256, 3)
void attn_flash(const bf16* __restrict__ qkv, const bf16* __restrict__ Vt,
                bf16* __restrict__ O) {
    const int bh = blockIdx.x;
    const int qt = gridDim.y - 1 - blockIdx.y;   // heaviest blocks dispatch first
    const int b = bh >> 4, h = bh & 15;
    const int tid = threadIdx.x, wave = tid >> 6, lane = tid & 63;
    const int lo = lane & 15, hi = lane >> 4;
    __shared__ __align__(16) bf16 sQ[64 * 64];
    __shared__ __align__(16) bf16 sK[2][64 * 64];
    __shared__ __align__(16) bf16 sV[2][64 * 64];
    __shared__ __align__(16) bf16 sP[4][16 * 64];

    const float LOG2E = 1.44269504088896340736f;
    const float slope2 = exp2f(-0.5f * (float)(h + 1)) * LOG2E;  // log2-domain slope
    const float qscale = 0.125f * LOG2E;
    const float SHIFT = 34.0f;   // fixed softmax shift (log2); exact by invariance
    const int q0 = qt * 64;
    const bf16* Qb = qkv + (size_t)b * LSEQ * QLD + h * DH;       // q slice
    const bf16* Kb = Qb + DM;                                      // k slice
    const bf16* Vb = Vt + (size_t)bh * DH * LSEQ;

    const int s0 = wave * 2, s1 = wave * 2 + 1;
    auto stageKV = [&](int kt, int buf) {
        load_lds16(Kb + (size_t)(kt * 64 + s0 * 8 + (lane >> 3)) * QLD + (lane & 7) * 8, &sK[buf][s0 * 512]);
        load_lds16(Kb + (size_t)(kt * 64 + s1 * 8 + (lane >> 3)) * QLD + (lane & 7) * 8, &sK[buf][s1 * 512]);
        load_lds16(Vb + (size_t)(s0 * 8 + (lane >> 3)) * LSEQ + kt * 64 + (lane & 7) * 8, &sV[buf][s0 * 512]);
        load_lds16(Vb + (size_t)(s1 * 8 + (lane >> 3)) * LSEQ + kt * 64 + (lane & 7) * 8, &sV[buf][s1 * 512]);
    };

#pragma unroll
    for (int i = 0; i < 2; ++i) {
        const int s = wave * 2 + i;
        load_lds16(Qb + (size_t)(q0 + s * 8 + (lane >> 3)) * QLD + (lane & 7) * 8, &sQ[s * 512]);
    }
    __syncthreads();
    bf16x8 aq0 = *(const bf16x8*)&sQ[(wave * 16 + lo) * 64 + hi * 8];
    bf16x8 aq1 = *(const bf16x8*)&sQ[(wave * 16 + lo) * 64 + 32 + hi * 8];

    bf16x8 vone;
#pragma unroll
    for (int t = 0; t < 8; t++) vone[t] = (__bf16)1.0f;

    f32x4 accO[4];
#pragma unroll
    for (int j = 0; j < 4; j++) accO[j] = (f32x4){0.f, 0.f, 0.f, 0.f};
    f32x4 accL = (f32x4){0.f, 0.f, 0.f, 0.f};
    const int irow0 = q0 + wave * 16 + hi * 4;

    float cbase[4];
#pragma unroll
    for (int r = 0; r < 4; r++) cbase[r] = slope2 * (float)(lo - (irow0 + r)) - SHIFT;
    const float jadd1 = slope2 * 16.f;
    const float kadd = slope2 * 64.f;

    stageKV(0, 0);
    for (int kt = 0; kt <= qt; ++kt) {
        const int bc = kt & 1, bn = bc ^ 1;
        if (kt < qt) {
            stageKV(kt + 1, bn);
            asm volatile("s_waitcnt vmcnt(4)" ::: "memory");
        } else {
            asm volatile("s_waitcnt vmcnt(0)" ::: "memory");
        }
        asm volatile("s_barrier" ::: "memory");   // B1: tile kt visible

        const bool diag = (kt == qt);
#pragma unroll
        for (int j = 0; j < 4; j++) {
            bf16x8 bk0 = *(const bf16x8*)&sK[bc][(j * 16 + lo) * 64 + hi * 8];
            bf16x8 bk1 = *(const bf16x8*)&sK[bc][(j * 16 + lo) * 64 + 32 + hi * 8];
            f32x4 z = (f32x4){0.f, 0.f, 0.f, 0.f};
            z = __builtin_amdgcn_mfma_f32_16x16x32_bf16(aq0, bk0, z, 0, 0, 0);
            z = __builtin_amdgcn_mfma_f32_16x16x32_bf16(aq1, bk1, z, 0, 0, 0);
            const float cj = (float)j * jadd1;
            if (diag) {
                const int jg = kt * 64 + j * 16 + lo;
#pragma unroll
                for (int r = 0; r < 4; r++) {
                    const float pv = (jg > irow0 + r) ? 0.f
                        : exp2f(fmaf(z[r], qscale, cbase[r] + cj));
                    sP[wave][(hi * 4 + r) * 64 + j * 16 + lo] = __float2bfloat16(pv);
                }
            } else {
#pragma unroll
                for (int r = 0; r < 4; r++) {
                    const float pv = exp2f(fmaf(z[r], qscale, cbase[r] + cj));
                    sP[wave][(hi * 4 + r) * 64 + j * 16 + lo] = __float2bfloat16(pv);
                }
            }
        }
#pragma unroll
        for (int r = 0; r < 4; r++) cbase[r] += kadd;
        bf16x8 ap0 = *(const bf16x8*)&sP[wave][lo * 64 + hi * 8];
        bf16x8 ap1 = *(const bf16x8*)&sP[wave][lo * 64 + 32 + hi * 8];
        accL = __builtin_amdgcn_mfma_f32_16x16x32_bf16(ap0, vone, accL, 0, 0, 0);
        accL = __builtin_amdgcn_mfma_f32_16x16x32_bf16(ap1, vone, accL, 0, 0, 0);
#pragma unroll
        for (int j = 0; j < 4; j++) {
            bf16x8 bv0 = *(const bf16x8*)&sV[bc][(j * 16 + lo) * 64 + hi * 8];
            bf16x8 bv1 = *(const bf16x8*)&sV[bc][(j * 16 + lo) * 64 + 32 + hi * 8];
            accO[j] = __builtin_amdgcn_mfma_f32_16x16x32_bf16(ap0, bv0, accO[j], 0, 0, 0);
            accO[j] = __builtin_amdgcn_mfma_f32_16x16x32_bf16(ap1, bv1, accO[j], 0, 0, 0);
        }
        asm volatile("s_barrier" ::: "memory");   // B2: reads of bc done
    }
    bf16* Ob = O + (size_t)b * LSEQ * DM + (size_t)h * DH;
#pragma unroll
    for (int r = 0; r < 4; r++) {
        const float inv = 1.0f / accL[r];
        const int row = q0 + wave * 16 + hi * 4 + r;
#pragma unroll
        for (int j = 0; j < 4; j++)
            Ob[(size_t)row * DM + j * 16 + lo] = __float2bfloat16(accO[j][r] * inv);
    }
}

// ---------------- launch ----------------------------------------------------
extern "C" void kernel_launch(void* const* d_in, const int* in_sizes, int n_in,
                              void* d_out, int out_size, void* d_ws, size_t ws_size,
                              hipStream_t stream) {
    const float* x      = (const float*)d_in[0];
    const float* w_qkv  = (const float*)d_in[3];
    const float* b_qkv  = (const float*)d_in[4];
    const float* w_o    = (const float*)d_in[5];
    const float* b_o    = (const float*)d_in[6];
    const float* scale1 = (const float*)d_in[7];
    const float* scale2 = (const float*)d_in[8];
    const float* w1     = (const float*)d_in[9];
    const float* b1     = (const float*)d_in[10];
    const float* w2     = (const float*)d_in[11];
    const float* b2     = (const float*)d_in[12];
    float* out = (float*)d_out;

    uint8_t* w = (uint8_t*)d_ws;
    size_t off = 0;
    auto take = [&](size_t bytes) { void* p = w + off; off += (bytes + 255) & ~(size_t)255; return p; };
    bf16* xn    = (bf16*)take((size_t)MROWS * DM * 2);
    bf16* wqkvT = (bf16*)take((size_t)3 * DM * DM * 2);
    bf16* woT   = (bf16*)take((size_t)DM * DM * 2);
    bf16* w1T   = (bf16*)take((size_t)2 * HID * DM * 2);
    bf16* w2T   = (bf16*)take((size_t)DM * HID * 2);
    bf16* qkvb  = (bf16*)take((size_t)MROWS * QLD * 2);
    bf16* vt    = (bf16*)take((size_t)MROWS * DM * 2);
    bf16* ao    = (bf16*)take((size_t)MROWS * DM * 2);
    float* x1   = (float*)take((size_t)MROWS * DM * 4);
    bf16* xn2   = (bf16*)take((size_t)MROWS * DM * 2);
    bf16* ffn   = (bf16*)take((size_t)MROWS * HID * 2);
    bf16* part1 = (bf16*)take((size_t)3 * MROWS * DM * 2);   // O-proj partials (bf16)
    bf16* part2 = (bf16*)take((size_t)3 * MROWS * DM * 2);   // FFN2 partials (bf16)

    // weights transpose + first rmsnorm in one dispatch
    transpose_all<<<16384 + MROWS, 256, 0, stream>>>(w_qkv, w_o, w1, w2,
                                                     wqkvT, woT, w1T, w2T,
                                                     x, scale1, xn);

    // QKV: M=4096, N=3072, K=1024  (768 blocks)
    EpiBiasBF16 e1{b_qkv, qkvb, QLD};
    gemm_bt<DM, 24, 1, EpiBiasBF16><<<32 * 24, 256, 0, stream>>>(xn, wqkvT, e1);

    v_transpose<<<dim3(LSEQ / 32, DH / 32, BB * NH), 256, 0, stream>>>(qkvb, vt);
    attn_flash<<<dim3(BB * NH, LSEQ / 64), 256, 0, stream>>>(qkvb, vt, ao);

    // O-proj split-K x3: 768 blocks -> bf16 partials, then fused reduce+rmsnorm
    EpiStoreBF16 e2{part1};
    gemm_bt<DM, 8, 3, EpiStoreBF16><<<3 * 32 * 8, 256, 0, stream>>>(ao, woT, e2);
    oproj_reduce_rmsnorm<<<MROWS, 256, 0, stream>>>(part1, b_o, x, scale2, x1, xn2);

    // FFN1+SwiGLU: M=4096, N=8192, K=1024  (2048 blocks, 128x128)
    EpiSwiGLU e3{b1, ffn};
    gemm_bt<DM, 64, 1, EpiSwiGLU><<<32 * 64, 256, 0, stream>>>(xn2, w1T, e3);

    // FFN2 split-K x3: 768 blocks -> bf16 partials, then reduce + bias + resid
    EpiStoreBF16 e4{part2};
    gemm_bt<HID, 8, 3, EpiStoreBF16><<<3 * 32 * 8, 256, 0, stream>>>(ffn, w2T, e4);
    ffn2_reduce<<<MROWS, 256, 0, stream>>>(part2, b2, x1, out);
}